// Round 6
// baseline (394.974 us; speedup 1.0000x reference)
//
#include <hip/hip_runtime.h>
#include <stdint.h>

#define N_NODES 50000
#define N_EDGES 800000
#define IN_F 128
#define HEADS 8
#define HEAD_DIM 16
#define ALPHA 0.2f
#define EPSV 1e-6f

// ---------------- init: zero deg
__global__ __launch_bounds__(256) void k_init(int* __restrict__ deg) {
    int i = blockIdx.x * 256 + threadIdx.x;
    if (i < N_NODES) deg[i] = 0;
}

// ---------------- wt: transpose W[h][f][d] -> WT[c][f]  (c = h*16+d)
__global__ __launch_bounds__(256) void k_wt(const float* __restrict__ W,
                                            float* __restrict__ WT) {
    int i = blockIdx.x * 256 + threadIdx.x;   // 64 blocks * 256 = 16384
    int c = i >> 7, f = i & 127;
    WT[i] = W[(c >> 4) * 2048 + f * 16 + (c & 15)];
}

// ---------------- k1: h = x @ W via scalar-broadcast W, x in VGPRs
// lane = node (64 nodes/block, shared by 4 waves); wave w computes cols [32w,32w+32)
// = heads 2w, 2w+1 -> per-wave s_src/s_tgt, no cross-wave combine.
__global__ __launch_bounds__(256) void k1_gemm(const float* __restrict__ x,
                                               const float* __restrict__ WT,
                                               const float* __restrict__ a,
                                               float* __restrict__ h,
                                               float* __restrict__ s_src,
                                               float* __restrict__ s_tgt) {
    int t = threadIdx.x;
    int wave = t >> 6, lane = t & 63;
    int n = blockIdx.x * 64 + lane;           // 782 blocks: 782*64 = 50048 >= 50000
    bool valid = (n < N_NODES);

    float xrf[128];
    {
        const float4* xg = (const float4*)(x + (size_t)n * 128);
#pragma unroll
        for (int j = 0; j < 32; j++) {
            float4 v = valid ? xg[j] : make_float4(0.f, 0.f, 0.f, 0.f);
            ((float4*)xrf)[j] = v;
        }
    }

    int cbase = wave * 32;
    float ps0 = 0.f, pt0 = 0.f, ps1 = 0.f, pt1 = 0.f;
#pragma unroll 1
    for (int cp = 0; cp < 16; cp++) {
        int c0 = cbase + 2 * cp, c1 = c0 + 1;
        const float* wt0 = WT + (size_t)c0 * 128;
        const float* wt1 = WT + (size_t)c1 * 128;
        float a0e = 0.f, a0o = 0.f, a1e = 0.f, a1o = 0.f;
#pragma unroll
        for (int f = 0; f < 128; f += 2) {
            a0e = fmaf(xrf[f],     wt0[f],     a0e);
            a0o = fmaf(xrf[f + 1], wt0[f + 1], a0o);
            a1e = fmaf(xrf[f],     wt1[f],     a1e);
            a1o = fmaf(xrf[f + 1], wt1[f + 1], a1o);
        }
        float h0 = a0e + a0o, h1 = a1e + a1o;
        if (valid) *(float2*)(h + (size_t)n * 128 + c0) = make_float2(h0, h1);

        int hd = c0 >> 4, d0 = c0 & 15;       // c1 same head, d0+1
        float as0 = a[hd * 32 + d0],     at0 = a[hd * 32 + 16 + d0];
        float as1 = a[hd * 32 + d0 + 1], at1 = a[hd * 32 + 16 + d0 + 1];
        float pss = fmaf(h0, as0, h1 * as1);
        float ptt = fmaf(h0, at0, h1 * at1);
        if (cp < 8) { ps0 += pss; pt0 += ptt; }
        else        { ps1 += pss; pt1 += ptt; }
    }
    if (valid) {
        int hh = 2 * wave;
        s_src[(size_t)n * 8 + hh]     = ps0;  s_tgt[(size_t)n * 8 + hh]     = pt0;
        s_src[(size_t)n * 8 + hh + 1] = ps1;  s_tgt[(size_t)n * 8 + hh + 1] = pt1;
    }
}

// ---------------- maxred stage 1: per-block partial per-head maxes (no atomics)
__global__ __launch_bounds__(256) void k_maxred1(const float* __restrict__ s_src,
                                                 const float* __restrict__ s_tgt,
                                                 float* __restrict__ part_ss,
                                                 float* __restrict__ part_st) {
    __shared__ float red[2][4][8];
    int t = threadIdx.x;
    int i = blockIdx.x * 256 + t;   // 1563*256 >= 400000
    float vs = -INFINITY, vt = -INFINITY;
    if (i < N_NODES * 8) { vs = s_src[i]; vt = s_tgt[i]; }
#pragma unroll
    for (int off = 8; off < 64; off <<= 1) {
        vs = fmaxf(vs, __shfl_xor(vs, off, 64));
        vt = fmaxf(vt, __shfl_xor(vt, off, 64));
    }
    int lane = t & 63, wave = t >> 6;
    if (lane < 8) { red[0][wave][lane] = vs; red[1][wave][lane] = vt; }
    __syncthreads();
    if (t < 8) {
        float m = fmaxf(fmaxf(red[0][0][t], red[0][1][t]),
                        fmaxf(red[0][2][t], red[0][3][t]));
        part_ss[blockIdx.x * 8 + t] = m;
    } else if (t < 16) {
        int j = t - 8;
        float m = fmaxf(fmaxf(red[1][0][j], red[1][1][j]),
                        fmaxf(red[1][2][j], red[1][3][j]));
        part_st[blockIdx.x * 8 + j] = m;
    }
}

// ---------------- maxred stage 2: one block reduces 1563*8 partials
__global__ __launch_bounds__(256) void k_maxred2(const float* __restrict__ part_ss,
                                                 const float* __restrict__ part_st,
                                                 float* __restrict__ maxss,
                                                 float* __restrict__ maxst) {
    __shared__ float red[2][4][8];
    int t = threadIdx.x;
    const int TOT = 1563 * 8;
    float vs = -INFINITY, vt = -INFINITY;
    for (int j = t; j < TOT; j += 256) {   // stride 256 % 8 == 0 keeps head = t&7
        vs = fmaxf(vs, part_ss[j]);
        vt = fmaxf(vt, part_st[j]);
    }
#pragma unroll
    for (int off = 8; off < 64; off <<= 1) {
        vs = fmaxf(vs, __shfl_xor(vs, off, 64));
        vt = fmaxf(vt, __shfl_xor(vt, off, 64));
    }
    int lane = t & 63, wave = t >> 6;
    if (lane < 8) { red[0][wave][lane] = vs; red[1][wave][lane] = vt; }
    __syncthreads();
    if (t < 8) {
        maxss[t] = fmaxf(fmaxf(red[0][0][t], red[0][1][t]),
                         fmaxf(red[0][2][t], red[0][3][t]));
    } else if (t < 16) {
        int j = t - 8;
        maxst[j] = fmaxf(fmaxf(red[1][0][j], red[1][1][j]),
                         fmaxf(red[1][2][j], red[1][3][j]));
    }
}

// ---------------- hist: deg[tgt]++
__global__ __launch_bounds__(256) void k_hist(const int* __restrict__ tgtA,
                                              int* __restrict__ deg) {
    int e = blockIdx.x * 256 + threadIdx.x;
    atomicAdd(&deg[tgtA[e]], 1);
}

// ---------------- scan1: per-block (256-node chunk) sums
__global__ __launch_bounds__(256) void k_scan1(const int* __restrict__ deg,
                                               int* __restrict__ bsum) {
    __shared__ int wsum[4];
    int t = threadIdx.x;
    int idx = blockIdx.x * 256 + t;
    int v = (idx < N_NODES) ? deg[idx] : 0;
#pragma unroll
    for (int off = 1; off < 64; off <<= 1) v += __shfl_xor(v, off, 64);
    int lane = t & 63, w = t >> 6;
    if (lane == 0) wsum[w] = v;
    __syncthreads();
    if (t == 0) bsum[blockIdx.x] = wsum[0] + wsum[1] + wsum[2] + wsum[3];
}

// ---------------- scan2: exclusive scan of 196 block sums
__global__ __launch_bounds__(256) void k_scan2(const int* __restrict__ bsum,
                                               int* __restrict__ boff,
                                               int* __restrict__ rowptr) {
    __shared__ int wsum[4];
    __shared__ int woff[4];
    int t = threadIdx.x, lane = t & 63, w = t >> 6;
    int v = (t < 196) ? bsum[t] : 0;
    int inc = v;
#pragma unroll
    for (int off = 1; off < 64; off <<= 1) {
        int nn = __shfl_up(inc, off, 64);
        if (lane >= off) inc += nn;
    }
    if (lane == 63) wsum[w] = inc;
    __syncthreads();
    if (t == 0) {
        woff[0] = 0;
        woff[1] = wsum[0];
        woff[2] = wsum[0] + wsum[1];
        woff[3] = wsum[0] + wsum[1] + wsum[2];
    }
    __syncthreads();
    if (t < 196) boff[t] = woff[w] + inc - v;
    if (t == 0) rowptr[N_NODES] = N_EDGES;
}

// ---------------- scan3: local exclusive scan + block offset -> rowptr/cursor
__global__ __launch_bounds__(256) void k_scan3(const int* __restrict__ deg,
                                               const int* __restrict__ boff,
                                               int* __restrict__ rowptr,
                                               int* __restrict__ cursor) {
    __shared__ int wsum[4];
    __shared__ int woff[4];
    int t = threadIdx.x, lane = t & 63, w = t >> 6;
    int idx = blockIdx.x * 256 + t;
    int v = (idx < N_NODES) ? deg[idx] : 0;
    int inc = v;
#pragma unroll
    for (int off = 1; off < 64; off <<= 1) {
        int nn = __shfl_up(inc, off, 64);
        if (lane >= off) inc += nn;
    }
    if (lane == 63) wsum[w] = inc;
    __syncthreads();
    if (t == 0) {
        woff[0] = 0;
        woff[1] = wsum[0];
        woff[2] = wsum[0] + wsum[1];
        woff[3] = wsum[0] + wsum[1] + wsum[2];
    }
    __syncthreads();
    int excl = boff[blockIdx.x] + woff[w] + inc - v;
    if (idx < N_NODES) { rowptr[idx] = excl; cursor[idx] = excl; }
}

// ---------------- scatter: src_sorted by tgt (lean, 4-edge ILP)
__global__ __launch_bounds__(256) void k_scatter(const int* __restrict__ srcA,
                                                 const int* __restrict__ tgtA,
                                                 int* __restrict__ cursor,
                                                 int* __restrict__ src_sorted) {
    int base = blockIdx.x * 1024 + threadIdx.x;
    int e0 = base, e1 = base + 256, e2 = base + 512, e3 = base + 768;
    if (e3 < N_EDGES) {
        int s0 = srcA[e0], s1 = srcA[e1], s2 = srcA[e2], s3 = srcA[e3];
        int t0 = tgtA[e0], t1 = tgtA[e1], t2 = tgtA[e2], t3 = tgtA[e3];
        int p0 = atomicAdd(&cursor[t0], 1);
        int p1 = atomicAdd(&cursor[t1], 1);
        int p2 = atomicAdd(&cursor[t2], 1);
        int p3 = atomicAdd(&cursor[t3], 1);
        src_sorted[p0] = s0;
        src_sorted[p1] = s1;
        src_sorted[p2] = s2;
        src_sorted[p3] = s3;
    } else {
#pragma unroll
        for (int k = 0; k < 4; k++) {
            int e = base + k * 256;
            if (e < N_EDGES) {
                int s = srcA[e], tg = tgtA[e];
                int p = atomicAdd(&cursor[tg], 1);
                src_sorted[p] = s;
            }
        }
    }
}

// ---------------- fused: per-node atomic-free softmax + aggregation + bias
// one wave per node; lane owns cols 2*lane, 2*lane+1 (single head = lane>>3)
__global__ __launch_bounds__(256) void k_fused(const int* __restrict__ rowptr,
                                               const int* __restrict__ src_sorted,
                                               const float* __restrict__ s_src,
                                               const float* __restrict__ s_tgt,
                                               const float* __restrict__ maxss,
                                               const float* __restrict__ maxst,
                                               const float* __restrict__ h,
                                               const float* __restrict__ bias,
                                               float* __restrict__ outb) {
    int t = threadIdx.x;
    int wave = t >> 6, lane = t & 63;
    int n = blockIdx.x * 4 + wave;   // 12500*4 == 50000
    int head = lane >> 3;
    int c = 2 * lane;

    float mh = maxss[head] + maxst[head];
    float st = s_tgt[(size_t)n * 8 + head];
    int begin = rowptr[n], end = rowptr[n + 1];

    float accx = 0.f, accy = 0.f, den = 0.f;
    int e = begin;
    for (; e + 1 < end; e += 2) {
        int sA = src_sorted[e];
        int sB = src_sorted[e + 1];
        float ssA = s_src[(size_t)sA * 8 + head];
        float ssB = s_src[(size_t)sB * 8 + head];
        float2 hA = *(const float2*)(h + (size_t)sA * 128 + c);
        float2 hB = *(const float2*)(h + (size_t)sB * 128 + c);
        float vA = ssA + st; vA = vA >= 0.f ? vA : ALPHA * vA;
        float vB = ssB + st; vB = vB >= 0.f ? vB : ALPHA * vB;
        float exA = __expf(fminf(fmaxf(vA - mh, -20.f), 20.f));
        float exB = __expf(fminf(fmaxf(vB - mh, -20.f), 20.f));
        den += exA + exB;
        accx = fmaf(exA, hA.x, fmaf(exB, hB.x, accx));
        accy = fmaf(exA, hA.y, fmaf(exB, hB.y, accy));
    }
    if (e < end) {
        int sA = src_sorted[e];
        float ssA = s_src[(size_t)sA * 8 + head];
        float2 hA = *(const float2*)(h + (size_t)sA * 128 + c);
        float vA = ssA + st; vA = vA >= 0.f ? vA : ALPHA * vA;
        float exA = __expf(fminf(fmaxf(vA - mh, -20.f), 20.f));
        den += exA;
        accx = fmaf(exA, hA.x, accx);
        accy = fmaf(exA, hA.y, accy);
    }
    float r = 1.f / (den + EPSV);
    float2 o;
    o.x = accx * r + bias[c];
    o.y = accy * r + bias[c + 1];
    *(float2*)(outb + (size_t)n * 128 + c) = o;
}

extern "C" void kernel_launch(void* const* d_in, const int* in_sizes, int n_in,
                              void* d_out, int out_size, void* d_ws, size_t ws_size,
                              hipStream_t stream) {
    const float* x    = (const float*)d_in[0];
    const int*   ei   = (const int*)d_in[1];
    const float* W    = (const float*)d_in[2];
    const float* a    = (const float*)d_in[3];
    const float* bias = (const float*)d_in[4];
    float* outb = (float*)d_out;

    char* ws = (char*)d_ws;
    // layout (bytes):
    float* h          = (float*)(ws);                    // 25,600,000
    float* s_src      = (float*)(ws + 25600000);         //  1,600,000
    float* s_tgt      = (float*)(ws + 27200000);         //  1,600,000
    int*   deg        = (int*)  (ws + 28800000);         //    200,064
    int*   rowptr     = (int*)  (ws + 29000064);         //    200,064
    int*   cursor     = (int*)  (ws + 29200128);         //    200,064
    int*   src_sorted = (int*)  (ws + 29400192);         //  3,200,000
    int*   bsum       = (int*)  (ws + 32600192);         //      1,024
    int*   boff       = (int*)  (ws + 32601216);         //      1,024
    float* part_ss    = (float*)(ws + 32602240);         //     50,176
    float* part_st    = (float*)(ws + 32652416);         //     50,176
    float* maxss      = (float*)(ws + 32702592);         //         32
    float* maxst      = (float*)(ws + 32702624);         //         32
    float* WT         = (float*)(ws + 32702656);         //     65,536

    const int* srcA = ei;
    const int* tgtA = ei + N_EDGES;

    hipLaunchKernelGGL(k_init,    dim3(196),   dim3(256), 0, stream, deg);
    hipLaunchKernelGGL(k_wt,      dim3(64),    dim3(256), 0, stream, W, WT);
    hipLaunchKernelGGL(k1_gemm,   dim3(782),   dim3(256), 0, stream, x, WT, a, h, s_src, s_tgt);
    hipLaunchKernelGGL(k_hist,    dim3(3125),  dim3(256), 0, stream, tgtA, deg);
    hipLaunchKernelGGL(k_maxred1, dim3(1563),  dim3(256), 0, stream, s_src, s_tgt, part_ss, part_st);
    hipLaunchKernelGGL(k_maxred2, dim3(1),     dim3(256), 0, stream, part_ss, part_st, maxss, maxst);
    hipLaunchKernelGGL(k_scan1,   dim3(196),   dim3(256), 0, stream, deg, bsum);
    hipLaunchKernelGGL(k_scan2,   dim3(1),     dim3(256), 0, stream, bsum, boff, rowptr);
    hipLaunchKernelGGL(k_scan3,   dim3(196),   dim3(256), 0, stream, deg, boff, rowptr, cursor);
    hipLaunchKernelGGL(k_scatter, dim3(782),   dim3(256), 0, stream, srcA, tgtA, cursor, src_sorted);
    hipLaunchKernelGGL(k_fused,   dim3(12500), dim3(256), 0, stream, rowptr, src_sorted, s_src, s_tgt, maxss, maxst, h, bias, outb);
}

// Round 7
// 340.210 us; speedup vs baseline: 1.1610x; 1.1610x over previous
//
#include <hip/hip_runtime.h>
#include <stdint.h>

#define N_NODES 50000
#define N_EDGES 800000
#define IN_F 128
#define HEADS 8
#define HEAD_DIM 16
#define ALPHA 0.2f
#define EPSV 1e-6f

// ---------------- init: zero deg
__global__ __launch_bounds__(256) void k_init(int* __restrict__ deg) {
    int i = blockIdx.x * 256 + threadIdx.x;
    if (i < N_NODES) deg[i] = 0;
}

// ---------------- wt: transpose W[h][f][d] -> WT[c][f]  (c = h*16+d)
__global__ __launch_bounds__(256) void k_wt(const float* __restrict__ W,
                                            float* __restrict__ WT) {
    int i = blockIdx.x * 256 + threadIdx.x;   // 64 blocks * 256 = 16384
    int c = i >> 7, f = i & 127;
    WT[i] = W[(c >> 4) * 2048 + f * 16 + (c & 15)];
}

// ---------------- k1: h = x @ W via SCALAR W loads (blockIdx.y = col group)
// 64-thread blocks (1 wave); lane = node; block computes cols [32*by, 32*by+32)
// = heads 2*by, 2*by+1. WT row addresses depend only on blockIdx.y + loop
// counter -> provably uniform -> s_load; x row lives in 128 VGPRs.
__global__ __launch_bounds__(64, 1) void k1_gemm(const float* __restrict__ x,
                                                 const float* __restrict__ WT,
                                                 const float* __restrict__ a,
                                                 float* __restrict__ h,
                                                 float* __restrict__ s_src,
                                                 float* __restrict__ s_tgt) {
    int lane = threadIdx.x;
    int n = blockIdx.x * 64 + lane;           // 782*64 = 50048 >= 50000
    bool valid = (n < N_NODES);
    int cg = blockIdx.y;                      // 0..3

    float xrf[128];
    {
        const float4* xg = (const float4*)(x + (size_t)n * 128);
#pragma unroll
        for (int j = 0; j < 32; j++) {
            float4 v = valid ? xg[j] : make_float4(0.f, 0.f, 0.f, 0.f);
            ((float4*)xrf)[j] = v;
        }
    }

    int cbase = cg * 32;
    float ps0 = 0.f, pt0 = 0.f, ps1 = 0.f, pt1 = 0.f;
#pragma unroll 1
    for (int cp = 0; cp < 16; cp++) {
        int c0 = cbase + 2 * cp, c1 = c0 + 1;
        const float* wt0 = WT + (size_t)c0 * 128;   // uniform (blockIdx + cp)
        const float* wt1 = WT + (size_t)c1 * 128;   // uniform
        float a0e = 0.f, a0o = 0.f, a1e = 0.f, a1o = 0.f;
#pragma unroll
        for (int f = 0; f < 128; f += 2) {
            a0e = fmaf(xrf[f],     wt0[f],     a0e);
            a0o = fmaf(xrf[f + 1], wt0[f + 1], a0o);
            a1e = fmaf(xrf[f],     wt1[f],     a1e);
            a1o = fmaf(xrf[f + 1], wt1[f + 1], a1o);
        }
        float h0 = a0e + a0o, h1 = a1e + a1o;
        if (valid) *(float2*)(h + (size_t)n * 128 + c0) = make_float2(h0, h1);

        int hd = c0 >> 4, d0 = c0 & 15;       // c1 same head, d0+1
        float as0 = a[hd * 32 + d0],     at0 = a[hd * 32 + 16 + d0];
        float as1 = a[hd * 32 + d0 + 1], at1 = a[hd * 32 + 16 + d0 + 1];
        float pss = fmaf(h0, as0, h1 * as1);
        float ptt = fmaf(h0, at0, h1 * at1);
        if (cp < 8) { ps0 += pss; pt0 += ptt; }
        else        { ps1 += pss; pt1 += ptt; }
    }
    if (valid) {
        int hh = 2 * cg;
        s_src[(size_t)n * 8 + hh]     = ps0;  s_tgt[(size_t)n * 8 + hh]     = pt0;
        s_src[(size_t)n * 8 + hh + 1] = ps1;  s_tgt[(size_t)n * 8 + hh + 1] = pt1;
    }
}

// ---------------- maxred stage 1: per-block partial per-head maxes (no atomics)
__global__ __launch_bounds__(256) void k_maxred1(const float* __restrict__ s_src,
                                                 const float* __restrict__ s_tgt,
                                                 float* __restrict__ part_ss,
                                                 float* __restrict__ part_st) {
    __shared__ float red[2][4][8];
    int t = threadIdx.x;
    int i = blockIdx.x * 256 + t;   // 1563*256 >= 400000
    float vs = -INFINITY, vt = -INFINITY;
    if (i < N_NODES * 8) { vs = s_src[i]; vt = s_tgt[i]; }
#pragma unroll
    for (int off = 8; off < 64; off <<= 1) {
        vs = fmaxf(vs, __shfl_xor(vs, off, 64));
        vt = fmaxf(vt, __shfl_xor(vt, off, 64));
    }
    int lane = t & 63, wave = t >> 6;
    if (lane < 8) { red[0][wave][lane] = vs; red[1][wave][lane] = vt; }
    __syncthreads();
    if (t < 8) {
        float m = fmaxf(fmaxf(red[0][0][t], red[0][1][t]),
                        fmaxf(red[0][2][t], red[0][3][t]));
        part_ss[blockIdx.x * 8 + t] = m;
    } else if (t < 16) {
        int j = t - 8;
        float m = fmaxf(fmaxf(red[1][0][j], red[1][1][j]),
                        fmaxf(red[1][2][j], red[1][3][j]));
        part_st[blockIdx.x * 8 + j] = m;
    }
}

// ---------------- maxred stage 2: one block reduces 1563*8 partials
__global__ __launch_bounds__(256) void k_maxred2(const float* __restrict__ part_ss,
                                                 const float* __restrict__ part_st,
                                                 float* __restrict__ maxss,
                                                 float* __restrict__ maxst) {
    __shared__ float red[2][4][8];
    int t = threadIdx.x;
    const int TOT = 1563 * 8;
    float vs = -INFINITY, vt = -INFINITY;
    for (int j = t; j < TOT; j += 256) {   // stride 256 % 8 == 0 keeps head = t&7
        vs = fmaxf(vs, part_ss[j]);
        vt = fmaxf(vt, part_st[j]);
    }
#pragma unroll
    for (int off = 8; off < 64; off <<= 1) {
        vs = fmaxf(vs, __shfl_xor(vs, off, 64));
        vt = fmaxf(vt, __shfl_xor(vt, off, 64));
    }
    int lane = t & 63, wave = t >> 6;
    if (lane < 8) { red[0][wave][lane] = vs; red[1][wave][lane] = vt; }
    __syncthreads();
    if (t < 8) {
        maxss[t] = fmaxf(fmaxf(red[0][0][t], red[0][1][t]),
                         fmaxf(red[0][2][t], red[0][3][t]));
    } else if (t < 16) {
        int j = t - 8;
        maxst[j] = fmaxf(fmaxf(red[1][0][j], red[1][1][j]),
                         fmaxf(red[1][2][j], red[1][3][j]));
    }
}

// ---------------- hist: deg[tgt]++
__global__ __launch_bounds__(256) void k_hist(const int* __restrict__ tgtA,
                                              int* __restrict__ deg) {
    int e = blockIdx.x * 256 + threadIdx.x;
    atomicAdd(&deg[tgtA[e]], 1);
}

// ---------------- scan1: per-block (256-node chunk) sums
__global__ __launch_bounds__(256) void k_scan1(const int* __restrict__ deg,
                                               int* __restrict__ bsum) {
    __shared__ int wsum[4];
    int t = threadIdx.x;
    int idx = blockIdx.x * 256 + t;
    int v = (idx < N_NODES) ? deg[idx] : 0;
#pragma unroll
    for (int off = 1; off < 64; off <<= 1) v += __shfl_xor(v, off, 64);
    int lane = t & 63, w = t >> 6;
    if (lane == 0) wsum[w] = v;
    __syncthreads();
    if (t == 0) bsum[blockIdx.x] = wsum[0] + wsum[1] + wsum[2] + wsum[3];
}

// ---------------- scan2: exclusive scan of 196 block sums
__global__ __launch_bounds__(256) void k_scan2(const int* __restrict__ bsum,
                                               int* __restrict__ boff,
                                               int* __restrict__ rowptr) {
    __shared__ int wsum[4];
    __shared__ int woff[4];
    int t = threadIdx.x, lane = t & 63, w = t >> 6;
    int v = (t < 196) ? bsum[t] : 0;
    int inc = v;
#pragma unroll
    for (int off = 1; off < 64; off <<= 1) {
        int nn = __shfl_up(inc, off, 64);
        if (lane >= off) inc += nn;
    }
    if (lane == 63) wsum[w] = inc;
    __syncthreads();
    if (t == 0) {
        woff[0] = 0;
        woff[1] = wsum[0];
        woff[2] = wsum[0] + wsum[1];
        woff[3] = wsum[0] + wsum[1] + wsum[2];
    }
    __syncthreads();
    if (t < 196) boff[t] = woff[w] + inc - v;
    if (t == 0) rowptr[N_NODES] = N_EDGES;
}

// ---------------- scan3: local exclusive scan + block offset -> rowptr/cursor
__global__ __launch_bounds__(256) void k_scan3(const int* __restrict__ deg,
                                               const int* __restrict__ boff,
                                               int* __restrict__ rowptr,
                                               int* __restrict__ cursor) {
    __shared__ int wsum[4];
    __shared__ int woff[4];
    int t = threadIdx.x, lane = t & 63, w = t >> 6;
    int idx = blockIdx.x * 256 + t;
    int v = (idx < N_NODES) ? deg[idx] : 0;
    int inc = v;
#pragma unroll
    for (int off = 1; off < 64; off <<= 1) {
        int nn = __shfl_up(inc, off, 64);
        if (lane >= off) inc += nn;
    }
    if (lane == 63) wsum[w] = inc;
    __syncthreads();
    if (t == 0) {
        woff[0] = 0;
        woff[1] = wsum[0];
        woff[2] = wsum[0] + wsum[1];
        woff[3] = wsum[0] + wsum[1] + wsum[2];
    }
    __syncthreads();
    int excl = boff[blockIdx.x] + woff[w] + inc - v;
    if (idx < N_NODES) { rowptr[idx] = excl; cursor[idx] = excl; }
}

// ---------------- scatter: src_sorted by tgt (lean, 4-edge ILP)
__global__ __launch_bounds__(256) void k_scatter(const int* __restrict__ srcA,
                                                 const int* __restrict__ tgtA,
                                                 int* __restrict__ cursor,
                                                 int* __restrict__ src_sorted) {
    int base = blockIdx.x * 1024 + threadIdx.x;
    int e0 = base, e1 = base + 256, e2 = base + 512, e3 = base + 768;
    if (e3 < N_EDGES) {
        int s0 = srcA[e0], s1 = srcA[e1], s2 = srcA[e2], s3 = srcA[e3];
        int t0 = tgtA[e0], t1 = tgtA[e1], t2 = tgtA[e2], t3 = tgtA[e3];
        int p0 = atomicAdd(&cursor[t0], 1);
        int p1 = atomicAdd(&cursor[t1], 1);
        int p2 = atomicAdd(&cursor[t2], 1);
        int p3 = atomicAdd(&cursor[t3], 1);
        src_sorted[p0] = s0;
        src_sorted[p1] = s1;
        src_sorted[p2] = s2;
        src_sorted[p3] = s3;
    } else {
#pragma unroll
        for (int k = 0; k < 4; k++) {
            int e = base + k * 256;
            if (e < N_EDGES) {
                int s = srcA[e], tg = tgtA[e];
                int p = atomicAdd(&cursor[tg], 1);
                src_sorted[p] = s;
            }
        }
    }
}

// ---------------- fused: per-node atomic-free softmax + aggregation + bias
// one wave per node; lane owns cols 2*lane, 2*lane+1 (single head = lane>>3)
__global__ __launch_bounds__(256) void k_fused(const int* __restrict__ rowptr,
                                               const int* __restrict__ src_sorted,
                                               const float* __restrict__ s_src,
                                               const float* __restrict__ s_tgt,
                                               const float* __restrict__ maxss,
                                               const float* __restrict__ maxst,
                                               const float* __restrict__ h,
                                               const float* __restrict__ bias,
                                               float* __restrict__ outb) {
    int t = threadIdx.x;
    int wave = t >> 6, lane = t & 63;
    int n = blockIdx.x * 4 + wave;   // 12500*4 == 50000
    int head = lane >> 3;
    int c = 2 * lane;

    float mh = maxss[head] + maxst[head];
    float st = s_tgt[(size_t)n * 8 + head];
    int begin = rowptr[n], end = rowptr[n + 1];

    float accx = 0.f, accy = 0.f, den = 0.f;
    int e = begin;
    for (; e + 1 < end; e += 2) {
        int sA = src_sorted[e];
        int sB = src_sorted[e + 1];
        float ssA = s_src[(size_t)sA * 8 + head];
        float ssB = s_src[(size_t)sB * 8 + head];
        float2 hA = *(const float2*)(h + (size_t)sA * 128 + c);
        float2 hB = *(const float2*)(h + (size_t)sB * 128 + c);
        float vA = ssA + st; vA = vA >= 0.f ? vA : ALPHA * vA;
        float vB = ssB + st; vB = vB >= 0.f ? vB : ALPHA * vB;
        float exA = __expf(fminf(fmaxf(vA - mh, -20.f), 20.f));
        float exB = __expf(fminf(fmaxf(vB - mh, -20.f), 20.f));
        den += exA + exB;
        accx = fmaf(exA, hA.x, fmaf(exB, hB.x, accx));
        accy = fmaf(exA, hA.y, fmaf(exB, hB.y, accy));
    }
    if (e < end) {
        int sA = src_sorted[e];
        float ssA = s_src[(size_t)sA * 8 + head];
        float2 hA = *(const float2*)(h + (size_t)sA * 128 + c);
        float vA = ssA + st; vA = vA >= 0.f ? vA : ALPHA * vA;
        float exA = __expf(fminf(fmaxf(vA - mh, -20.f), 20.f));
        den += exA;
        accx = fmaf(exA, hA.x, accx);
        accy = fmaf(exA, hA.y, accy);
    }
    float r = 1.f / (den + EPSV);
    float2 o;
    o.x = accx * r + bias[c];
    o.y = accy * r + bias[c + 1];
    *(float2*)(outb + (size_t)n * 128 + c) = o;
}

extern "C" void kernel_launch(void* const* d_in, const int* in_sizes, int n_in,
                              void* d_out, int out_size, void* d_ws, size_t ws_size,
                              hipStream_t stream) {
    const float* x    = (const float*)d_in[0];
    const int*   ei   = (const int*)d_in[1];
    const float* W    = (const float*)d_in[2];
    const float* a    = (const float*)d_in[3];
    const float* bias = (const float*)d_in[4];
    float* outb = (float*)d_out;

    char* ws = (char*)d_ws;
    // layout (bytes):
    float* h          = (float*)(ws);                    // 25,600,000
    float* s_src      = (float*)(ws + 25600000);         //  1,600,000
    float* s_tgt      = (float*)(ws + 27200000);         //  1,600,000
    int*   deg        = (int*)  (ws + 28800000);         //    200,064
    int*   rowptr     = (int*)  (ws + 29000064);         //    200,064
    int*   cursor     = (int*)  (ws + 29200128);         //    200,064
    int*   src_sorted = (int*)  (ws + 29400192);         //  3,200,000
    int*   bsum       = (int*)  (ws + 32600192);         //      1,024
    int*   boff       = (int*)  (ws + 32601216);         //      1,024
    float* part_ss    = (float*)(ws + 32602240);         //     50,176
    float* part_st    = (float*)(ws + 32652416);         //     50,176
    float* maxss      = (float*)(ws + 32702592);         //         32
    float* maxst      = (float*)(ws + 32702624);         //         32
    float* WT         = (float*)(ws + 32702656);         //     65,536

    const int* srcA = ei;
    const int* tgtA = ei + N_EDGES;

    hipLaunchKernelGGL(k_init,    dim3(196),      dim3(256), 0, stream, deg);
    hipLaunchKernelGGL(k_wt,      dim3(64),       dim3(256), 0, stream, W, WT);
    hipLaunchKernelGGL(k1_gemm,   dim3(782, 4),   dim3(64),  0, stream, x, WT, a, h, s_src, s_tgt);
    hipLaunchKernelGGL(k_hist,    dim3(3125),     dim3(256), 0, stream, tgtA, deg);
    hipLaunchKernelGGL(k_maxred1, dim3(1563),     dim3(256), 0, stream, s_src, s_tgt, part_ss, part_st);
    hipLaunchKernelGGL(k_maxred2, dim3(1),        dim3(256), 0, stream, part_ss, part_st, maxss, maxst);
    hipLaunchKernelGGL(k_scan1,   dim3(196),      dim3(256), 0, stream, deg, bsum);
    hipLaunchKernelGGL(k_scan2,   dim3(1),        dim3(256), 0, stream, bsum, boff, rowptr);
    hipLaunchKernelGGL(k_scan3,   dim3(196),      dim3(256), 0, stream, deg, boff, rowptr, cursor);
    hipLaunchKernelGGL(k_scatter, dim3(782),      dim3(256), 0, stream, srcA, tgtA, cursor, src_sorted);
    hipLaunchKernelGGL(k_fused,   dim3(12500),    dim3(256), 0, stream, rowptr, src_sorted, s_src, s_tgt, maxss, maxst, h, bias, outb);
}